// Round 6
// baseline (554.935 us; speedup 1.0000x reference)
//
#include <hip/hip_runtime.h>
#include <hip/hip_bf16.h>

#define B_SZ 512
#define I_SZ 7
#define D_SZ 512
#define J_SZ 64
#define E_SZ 128
#define N_SZ 8192
#define ITERS 10

typedef __attribute__((ext_vector_type(8))) short bf16x8;
typedef __attribute__((ext_vector_type(4))) float f32x4;

#if defined(__has_builtin)
#if __has_builtin(__builtin_amdgcn_cvt_pk_bf16_f32)
#define HAVE_CVT_PK_BF16 1
#endif
#endif

// Split a PAIR of fp32 into packed-bf16 hi and lo words (RNE both stages).
// hp low short = bf16(x0), high short = bf16(x1); same for lp with residuals.
__device__ inline void split2(float x0, float x1, unsigned& hp, unsigned& lp) {
#ifdef HAVE_CVT_PK_BF16
    auto h = __builtin_amdgcn_cvt_pk_bf16_f32(x0, x1);
    hp = __builtin_bit_cast(unsigned, h);
    union { unsigned u; float f; } b0, b1;
    b0.u = hp << 16;
    b1.u = hp & 0xFFFF0000u;
    auto l = __builtin_amdgcn_cvt_pk_bf16_f32(x0 - b0.f, x1 - b1.f);
    lp = __builtin_bit_cast(unsigned, l);
#else
    union { float f; unsigned u; } u0, u1;
    u0.f = x0; u1.f = x1;
    unsigned r0 = u0.u + 0x7FFF + ((u0.u >> 16) & 1);
    unsigned r1 = u1.u + 0x7FFF + ((u1.u >> 16) & 1);
    hp = __builtin_amdgcn_perm(r1, r0, 0x07060302);   // [r1.hi16 | r0.hi16]
    union { unsigned u; float f; } h0, h1;
    h0.u = r0 & 0xFFFF0000u;
    h1.u = r1 & 0xFFFF0000u;
    union { float f; unsigned u; } s0, s1;
    s0.f = x0 - h0.f; s1.f = x1 - h1.f;
    unsigned q0 = s0.u + 0x7FFF + ((s0.u >> 16) & 1);
    unsigned q1 = s1.u + 0x7FFF + ((s1.u >> 16) & 1);
    lp = __builtin_amdgcn_perm(q1, q0, 0x07060302);
#endif
}

// ---------------------------------------------------------------------------
// Kernel 1 (R11): vote GEMM = R5's measured-best structure + two validated fixes.
// fW[b,i,j,e] = sum_d f[b,i,d]*W[i,d,j,e].  Per i: C[512,8192]=A[512,512]*B.
//
// R10 post-mortem: regime is LATENCY-bound (all pipes <=30%); the only lever
// that has moved perf across 6 rounds is INDEPENDENT co-resident blocks.
// R5 (134us) had 2-4 blocks/CU; every 8-wave/lockstep design was 145-186us.
// So: 128x128 tile, BK=32, 256 threads (4 waves x 64x64), single-buffer LDS,
// 2 barriers/tile, full-tile prefetch distance (R5's loop verbatim), PLUS:
//  (a) R8-hardware-validated swizzle replaces the +8 pad: 32-short rows,
//      chunk pos = c ^ ((row>>1)&3); b128 granule = (4*row+pos) mod 8.
//      R8 measured 0 bank conflicts with byte-identical maps (vs R5's 1.1e7),
//      and LDS drops 40->32 KB.
//  (b) __launch_bounds__(256,4): 4 blocks/CU resident (16 waves/CU; each
//      SIMD holds 4 waves from 4 DIFFERENT blocks -> barrier stalls of one
//      block fill with another's MFMA). 128 KiB LDS total of 160.
// acc += Ahi*Bhi + Ahi*Blo + Alo*Bhi  (lo*lo dropped, same math as R5-R10).
// ---------------------------------------------------------------------------
__global__ __launch_bounds__(256, 4) void vote_gemm_mfma(
    const float* __restrict__ f,   // [B, I, D]
    const float* __restrict__ W,   // [I, D, N]
    float* __restrict__ fW)        // [B, I, N]
{
    const int i  = blockIdx.z;
    const int m0 = blockIdx.y * 128;
    const int n0 = blockIdx.x * 128;
    const int th = threadIdx.x;
    const int lane = th & 63;
    const int wave = th >> 6;
    const int wr   = wave >> 1;    // 0..1: 64-row half
    const int wc   = wave & 1;     // 0..1: 64-col half
    const int quad = lane >> 4;    // 0..3: k-chunk of the fragment
    const int lm   = lane & 15;

    __shared__ short Ah_s[128 * 32];   // 8 KiB each, 32 KiB total
    __shared__ short Al_s[128 * 32];
    __shared__ short Bh_s[128 * 32];
    __shared__ short Bl_s[128 * 32];

    // ---- staging map (R8-validated, 0 conflicts): thread -> (row sm, k-half kh)
    const int sm = th >> 1;        // A row m / B col n, 0..127
    const int kh = th & 1;         // 16-k half
    const int swz = (sm >> 1) & 3; // b128 granule swizzle (row bits 1..2)
    const int wo0 = sm * 32 + (((kh << 1) | 0) ^ swz) * 8;   // chunk 2kh
    const int wo1 = sm * 32 + (((kh << 1) | 1) ^ swz) * 8;   // chunk 2kh+1

    const float* aPtr = f + (size_t)(m0 + sm) * (I_SZ * D_SZ) + (size_t)i * D_SZ + kh * 16;
    const float* bPtr = W + (size_t)i * D_SZ * N_SZ + (size_t)(kh * 16) * N_SZ + n0 + sm;

    // ---- fragment read chunk position (same swizzle; row bits 1..2 = lm>>1) ----
    const int fpos8 = (quad ^ ((lm >> 1) & 3)) * 8;

    f32x4 acc[4][4];
#pragma unroll
    for (int a = 0; a < 4; ++a)
#pragma unroll
        for (int c = 0; c < 4; ++c)
            acc[a][c] = (f32x4){0.f, 0.f, 0.f, 0.f};

    float av[16], bv[16];
    auto stage_load = [&](int kt) {
        const float* pa = aPtr + kt * 32;
        float4 t0 = *(const float4*)(pa);
        float4 t1 = *(const float4*)(pa + 4);
        float4 t2 = *(const float4*)(pa + 8);
        float4 t3 = *(const float4*)(pa + 12);
        av[0]=t0.x;  av[1]=t0.y;  av[2]=t0.z;  av[3]=t0.w;
        av[4]=t1.x;  av[5]=t1.y;  av[6]=t1.z;  av[7]=t1.w;
        av[8]=t2.x;  av[9]=t2.y;  av[10]=t2.z; av[11]=t2.w;
        av[12]=t3.x; av[13]=t3.y; av[14]=t3.z; av[15]=t3.w;
        const float* pb = bPtr + (size_t)kt * 32 * N_SZ;
#pragma unroll
        for (int r = 0; r < 16; ++r) bv[r] = pb[(size_t)r * N_SZ];
    };

    // ---- prologue: loads for tile 0 ----
    stage_load(0);

    for (int t = 0; t < 16; ++t) {
        // ---- split tile t (VALU only; av/bv were prefetched last tile) ----
        uint4 ah0, al0, ah1, al1, bh0, bl0, bh1, bl1;
        split2(av[0],  av[1],  ah0.x, al0.x); split2(av[2],  av[3],  ah0.y, al0.y);
        split2(av[4],  av[5],  ah0.z, al0.z); split2(av[6],  av[7],  ah0.w, al0.w);
        split2(av[8],  av[9],  ah1.x, al1.x); split2(av[10], av[11], ah1.y, al1.y);
        split2(av[12], av[13], ah1.z, al1.z); split2(av[14], av[15], ah1.w, al1.w);
        split2(bv[0],  bv[1],  bh0.x, bl0.x); split2(bv[2],  bv[3],  bh0.y, bl0.y);
        split2(bv[4],  bv[5],  bh0.z, bl0.z); split2(bv[6],  bv[7],  bh0.w, bl0.w);
        split2(bv[8],  bv[9],  bh1.x, bl1.x); split2(bv[10], bv[11], bh1.y, bl1.y);
        split2(bv[12], bv[13], bh1.z, bl1.z); split2(bv[14], bv[15], bh1.w, bl1.w);

        __syncthreads();   // previous tile's fragment reads complete
        *(uint4*)&Ah_s[wo0] = ah0; *(uint4*)&Ah_s[wo1] = ah1;
        *(uint4*)&Al_s[wo0] = al0; *(uint4*)&Al_s[wo1] = al1;
        *(uint4*)&Bh_s[wo0] = bh0; *(uint4*)&Bh_s[wo1] = bh1;
        *(uint4*)&Bl_s[wo0] = bl0; *(uint4*)&Bl_s[wo1] = bl1;
        __syncthreads();   // staging visible

        // ---- issue next-tile loads; consumed at next tile's split (full cover) ----
        if (t < 15) stage_load(t + 1);

        // ---- fragments + MFMA ----
        bf16x8 Bf_h[4], Bf_l[4];
#pragma unroll
        for (int ns = 0; ns < 4; ++ns) {
            const int o = (wc * 64 + ns * 16 + lm) * 32 + fpos8;
            Bf_h[ns] = *(const bf16x8*)&Bh_s[o];
            Bf_l[ns] = *(const bf16x8*)&Bl_s[o];
        }
#pragma unroll
        for (int ms = 0; ms < 4; ++ms) {
            const int o = (wr * 64 + ms * 16 + lm) * 32 + fpos8;
            const bf16x8 Af_h = *(const bf16x8*)&Ah_s[o];
            const bf16x8 Af_l = *(const bf16x8*)&Al_s[o];
            __builtin_amdgcn_s_setprio(1);
#pragma unroll
            for (int ns = 0; ns < 4; ++ns) {
                acc[ms][ns] = __builtin_amdgcn_mfma_f32_16x16x32_bf16(Af_h, Bf_h[ns], acc[ms][ns], 0, 0, 0);
                acc[ms][ns] = __builtin_amdgcn_mfma_f32_16x16x32_bf16(Af_h, Bf_l[ns], acc[ms][ns], 0, 0, 0);
                acc[ms][ns] = __builtin_amdgcn_mfma_f32_16x16x32_bf16(Af_l, Bf_h[ns], acc[ms][ns], 0, 0, 0);
            }
            __builtin_amdgcn_s_setprio(0);
        }
    }

    // ---- write C: D layout col=lane&15, row=quad*4+reg (verified R5-R10) ----
#pragma unroll
    for (int ms = 0; ms < 4; ++ms) {
        const int rowb = m0 + wr * 64 + ms * 16 + quad * 4;
#pragma unroll
        for (int ns = 0; ns < 4; ++ns) {
            const int col = n0 + wc * 64 + ns * 16 + lm;
#pragma unroll
            for (int r = 0; r < 4; ++r)
                fW[((size_t)(rowb + r) * I_SZ + i) * N_SZ + col] = acc[ms][ns][r];
        }
    }
}

// ---------------------------------------------------------------------------
// Kernel 2: routing via Gram matrices (unchanged).
// ---------------------------------------------------------------------------
__global__ __launch_bounds__(1024) void routing_kernel(
    const float* __restrict__ fW,  // [B, I, N]
    const float* __restrict__ p,   // [B, I]
    float* __restrict__ c_out,     // [B, J, E]
    float* __restrict__ r_out)     // [B, I, J]
{
    const int b   = blockIdx.x;
    const int tid = threadIdx.x;
    const int j   = tid >> 4;      // 0..63
    const int sub = tid & 15;      // e-chunk [sub*8, sub*8+8)

    __shared__ float G_sh[64][49];
    __shared__ float s_sh[64][9];
    __shared__ float w_sh[2][64][9];
    __shared__ float p_sh[8];

    if (tid < I_SZ) p_sh[tid] = p[(size_t)b * I_SZ + tid];

    float4 fw[I_SZ][2];
    const float* base = fW + (size_t)b * I_SZ * N_SZ + j * E_SZ + sub * 8;
#pragma unroll
    for (int i = 0; i < I_SZ; ++i) {
        fw[i][0] = *(const float4*)(base + (size_t)i * N_SZ);
        fw[i][1] = *(const float4*)(base + (size_t)i * N_SZ + 4);
    }

    // ---- Phase 1: Gram + row sums (reduce over 16 sub-lanes) ----
#pragma unroll
    for (int i = 0; i < I_SZ; ++i) {
        float s = fw[i][0].x + fw[i][0].y + fw[i][0].z + fw[i][0].w
                + fw[i][1].x + fw[i][1].y + fw[i][1].z + fw[i][1].w;
        s += __shfl_xor(s, 1); s += __shfl_xor(s, 2);
        s += __shfl_xor(s, 4); s += __shfl_xor(s, 8);
        if (sub == 0) s_sh[j][i] = s;
#pragma unroll
        for (int i2 = i; i2 < I_SZ; ++i2) {
            float g = fw[i][0].x * fw[i2][0].x + fw[i][0].y * fw[i2][0].y
                    + fw[i][0].z * fw[i2][0].z + fw[i][0].w * fw[i2][0].w
                    + fw[i][1].x * fw[i2][1].x + fw[i][1].y * fw[i2][1].y
                    + fw[i][1].z * fw[i2][1].z + fw[i][1].w * fw[i2][1].w;
            g += __shfl_xor(g, 1); g += __shfl_xor(g, 2);
            g += __shfl_xor(g, 4); g += __shfl_xor(g, 8);
            if (sub == 0) { G_sh[j][i * 7 + i2] = g; G_sh[j][i2 * 7 + i] = g; }
        }
    }
    __syncthreads();

    // ---- Phase 2: 10 iterations on the 7x7 system ----
    for (int t = 0; t < ITERS; ++t) {
        if (tid < I_SZ * 64) {                 // waves 0..6
            const int ii = tid >> 6;
            const int jj = tid & 63;
            float l;
            if (t == 0) {
                l = s_sh[jj][ii];              // c0 = ones
            } else {
                const int rb = t & 1;
                l = 0.f;
#pragma unroll
                for (int i2 = 0; i2 < I_SZ; ++i2)
                    l = fmaf(w_sh[rb][jj][i2], G_sh[jj][ii * 7 + i2], l);
            }
            float mx = l;
#pragma unroll
            for (int off = 32; off > 0; off >>= 1)
                mx = fmaxf(mx, __shfl_xor(mx, off));
            float ex = __expf(l - mx);
            float sm = ex;
#pragma unroll
            for (int off = 32; off > 0; off >>= 1)
                sm += __shfl_xor(sm, off);
            float r = ex / sm;
            if (t == ITERS - 1)
                r_out[(size_t)b * (I_SZ * J_SZ) + ii * 64 + jj] = r;
            w_sh[(t + 1) & 1][jj][ii] = p_sh[ii] * r;
        }
        __syncthreads();
    }

    // ---- Phase 3: c from registers ----
    float4 a0 = make_float4(0.f, 0.f, 0.f, 0.f);
    float4 a1 = make_float4(0.f, 0.f, 0.f, 0.f);
#pragma unroll
    for (int i = 0; i < I_SZ; ++i) {
        float wv = w_sh[ITERS & 1][j][i];
        a0.x = fmaf(wv, fw[i][0].x, a0.x); a0.y = fmaf(wv, fw[i][0].y, a0.y);
        a0.z = fmaf(wv, fw[i][0].z, a0.z); a0.w = fmaf(wv, fw[i][0].w, a0.w);
        a1.x = fmaf(wv, fw[i][1].x, a1.x); a1.y = fmaf(wv, fw[i][1].y, a1.y);
        a1.z = fmaf(wv, fw[i][1].z, a1.z); a1.w = fmaf(wv, fw[i][1].w, a1.w);
    }
    float* dst = c_out + (size_t)b * N_SZ + j * E_SZ + sub * 8;
    *(float4*)(dst)     = a0;
    *(float4*)(dst + 4) = a1;
}

extern "C" void kernel_launch(void* const* d_in, const int* in_sizes, int n_in,
                              void* d_out, int out_size, void* d_ws, size_t ws_size,
                              hipStream_t stream) {
    const float* f = (const float*)d_in[0];   // [512,7,512]
    const float* p = (const float*)d_in[1];   // [512,7]
    const float* W = (const float*)d_in[2];   // [7,512,64,128]
    float* out = (float*)d_out;               // c (512*64*128) then r (512*7*64)
    float* fW  = (float*)d_ws;                // 117.4 MB scratch

    vote_gemm_mfma<<<dim3(N_SZ / 128, B_SZ / 128, I_SZ), 256, 0, stream>>>(f, W, fW);
    routing_kernel<<<B_SZ, 1024, 0, stream>>>(fW, p, out, out + (size_t)B_SZ * N_SZ);
}

// Round 7
// 340.662 us; speedup vs baseline: 1.6290x; 1.6290x over previous
//
#include <hip/hip_runtime.h>
#include <hip/hip_bf16.h>

#define B_SZ 512
#define I_SZ 7
#define D_SZ 512
#define J_SZ 64
#define E_SZ 128
#define N_SZ 8192
#define ITERS 10

typedef __attribute__((ext_vector_type(8))) short bf16x8;
typedef __attribute__((ext_vector_type(4))) float f32x4;

#if defined(__has_builtin)
#if __has_builtin(__builtin_amdgcn_cvt_pk_bf16_f32)
#define HAVE_CVT_PK_BF16 1
#endif
#endif

// Split a PAIR of fp32 into packed-bf16 hi and lo words (RNE both stages).
// hp low short = bf16(x0), high short = bf16(x1); same for lp with residuals.
__device__ inline void split2(float x0, float x1, unsigned& hp, unsigned& lp) {
#ifdef HAVE_CVT_PK_BF16
    auto h = __builtin_amdgcn_cvt_pk_bf16_f32(x0, x1);
    hp = __builtin_bit_cast(unsigned, h);
    union { unsigned u; float f; } b0, b1;
    b0.u = hp << 16;
    b1.u = hp & 0xFFFF0000u;
    auto l = __builtin_amdgcn_cvt_pk_bf16_f32(x0 - b0.f, x1 - b1.f);
    lp = __builtin_bit_cast(unsigned, l);
#else
    union { float f; unsigned u; } u0, u1;
    u0.f = x0; u1.f = x1;
    unsigned r0 = u0.u + 0x7FFF + ((u0.u >> 16) & 1);
    unsigned r1 = u1.u + 0x7FFF + ((u1.u >> 16) & 1);
    hp = __builtin_amdgcn_perm(r1, r0, 0x07060302);   // [r1.hi16 | r0.hi16]
    union { unsigned u; float f; } h0, h1;
    h0.u = r0 & 0xFFFF0000u;
    h1.u = r1 & 0xFFFF0000u;
    union { float f; unsigned u; } s0, s1;
    s0.f = x0 - h0.f; s1.f = x1 - h1.f;
    unsigned q0 = s0.u + 0x7FFF + ((s0.u >> 16) & 1);
    unsigned q1 = s1.u + 0x7FFF + ((s1.u >> 16) & 1);
    lp = __builtin_amdgcn_perm(q1, q0, 0x07060302);
#endif
}

// ---------------------------------------------------------------------------
// Kernel 1 (R12): R5's measured-best structure (134 us), ONLY delta = the
// hardware-validated conflict-free swizzle replacing the +8 pad.
// fW[b,i,j,e] = sum_d f[b,i,d]*W[i,d,j,e].  Per i: C[512,8192]=A[512,512]*B.
//
// R11 post-mortem: __launch_bounds__(256,4) capped unified regs at 128/wave
// -> 64 VGPR + 64 AGPR acc left no room for av/bv+frags -> scratch spill
// (WRITE_SIZE 115->713 MB, FETCH 86->352 MB, 400 us). Lesson: never constrain
// the allocator below the live-set (G6). This round: NO min-waves hint, no
// setprio — byte-for-byte R5 loop, natural ~80-VGPR allocation.
//
// Swizzle (validated 0 conflicts in R8 AND R11, byte-identical maps):
//   rows of 32 shorts (64 B); 8-short chunk c of row stored at position
//   c ^ ((row>>1)&3); b128 granule = (4*row + pos) mod 8. Staging writes
//   (4 rows x 2 kh per 8-lane group) and fragment reads (8 rows per group)
//   each tile all 8 granule slots. LDS 40->32 KB/block.
// acc += Ahi*Bhi + Ahi*Blo + Alo*Bhi  (lo*lo dropped: ~2^-18 rel).
// ---------------------------------------------------------------------------
__global__ __launch_bounds__(256) void vote_gemm_mfma(
    const float* __restrict__ f,   // [B, I, D]
    const float* __restrict__ W,   // [I, D, N]
    float* __restrict__ fW)        // [B, I, N]
{
    const int i  = blockIdx.z;
    const int m0 = blockIdx.y * 128;
    const int n0 = blockIdx.x * 128;
    const int th = threadIdx.x;
    const int lane = th & 63;
    const int wave = th >> 6;
    const int wr   = wave >> 1;    // 0..1: 64-row half
    const int wc   = wave & 1;     // 0..1: 64-col half
    const int quad = lane >> 4;    // 0..3: k-chunk of the fragment
    const int lm   = lane & 15;

    __shared__ short Ah_s[128 * 32];   // 8 KiB each, 32 KiB total
    __shared__ short Al_s[128 * 32];
    __shared__ short Bh_s[128 * 32];
    __shared__ short Bl_s[128 * 32];

    // ---- staging map: thread -> (row sm, k-half kh); same for A and B ----
    const int sm = th >> 1;        // A row m / B col n, 0..127
    const int kh = th & 1;         // 16-k half
    const int swz = (sm >> 1) & 3; // b128 granule swizzle (row bits 1..2)
    const int wo0 = sm * 32 + (((kh << 1) | 0) ^ swz) * 8;   // chunk 2kh
    const int wo1 = sm * 32 + (((kh << 1) | 1) ^ swz) * 8;   // chunk 2kh+1

    const float* aPtr = f + (size_t)(m0 + sm) * (I_SZ * D_SZ) + (size_t)i * D_SZ + kh * 16;
    const float* bPtr = W + (size_t)i * D_SZ * N_SZ + (size_t)(kh * 16) * N_SZ + n0 + sm;

    // ---- fragment read chunk position (same swizzle; row bits 1..2 = lm>>1) ----
    const int fpos8 = (quad ^ ((lm >> 1) & 3)) * 8;

    f32x4 acc[4][4];
#pragma unroll
    for (int a = 0; a < 4; ++a)
#pragma unroll
        for (int c = 0; c < 4; ++c)
            acc[a][c] = (f32x4){0.f, 0.f, 0.f, 0.f};

    float av[16], bv[16];
    auto stage_load = [&](int kt) {
        const float* pa = aPtr + kt * 32;
        float4 t0 = *(const float4*)(pa);
        float4 t1 = *(const float4*)(pa + 4);
        float4 t2 = *(const float4*)(pa + 8);
        float4 t3 = *(const float4*)(pa + 12);
        av[0]=t0.x;  av[1]=t0.y;  av[2]=t0.z;  av[3]=t0.w;
        av[4]=t1.x;  av[5]=t1.y;  av[6]=t1.z;  av[7]=t1.w;
        av[8]=t2.x;  av[9]=t2.y;  av[10]=t2.z; av[11]=t2.w;
        av[12]=t3.x; av[13]=t3.y; av[14]=t3.z; av[15]=t3.w;
        const float* pb = bPtr + (size_t)kt * 32 * N_SZ;
#pragma unroll
        for (int r = 0; r < 16; ++r) bv[r] = pb[(size_t)r * N_SZ];
    };

    // ---- prologue: loads for tile 0 ----
    stage_load(0);

    for (int t = 0; t < 16; ++t) {
        // ---- split tile t (VALU only; av/bv prefetched during tile t-1) ----
        uint4 ah0, al0, ah1, al1, bh0, bl0, bh1, bl1;
        split2(av[0],  av[1],  ah0.x, al0.x); split2(av[2],  av[3],  ah0.y, al0.y);
        split2(av[4],  av[5],  ah0.z, al0.z); split2(av[6],  av[7],  ah0.w, al0.w);
        split2(av[8],  av[9],  ah1.x, al1.x); split2(av[10], av[11], ah1.y, al1.y);
        split2(av[12], av[13], ah1.z, al1.z); split2(av[14], av[15], ah1.w, al1.w);
        split2(bv[0],  bv[1],  bh0.x, bl0.x); split2(bv[2],  bv[3],  bh0.y, bl0.y);
        split2(bv[4],  bv[5],  bh0.z, bl0.z); split2(bv[6],  bv[7],  bh0.w, bl0.w);
        split2(bv[8],  bv[9],  bh1.x, bl1.x); split2(bv[10], bv[11], bh1.y, bl1.y);
        split2(bv[12], bv[13], bh1.z, bl1.z); split2(bv[14], bv[15], bh1.w, bl1.w);

        __syncthreads();   // previous tile's fragment reads complete
        *(uint4*)&Ah_s[wo0] = ah0; *(uint4*)&Ah_s[wo1] = ah1;
        *(uint4*)&Al_s[wo0] = al0; *(uint4*)&Al_s[wo1] = al1;
        *(uint4*)&Bh_s[wo0] = bh0; *(uint4*)&Bh_s[wo1] = bh1;
        *(uint4*)&Bl_s[wo0] = bl0; *(uint4*)&Bl_s[wo1] = bl1;
        __syncthreads();   // staging visible

        // ---- issue next-tile loads (latency hides under MFMA below) ----
        if (t < 15) stage_load(t + 1);

        // ---- fragments + MFMA ----
        bf16x8 Bf_h[4], Bf_l[4];
#pragma unroll
        for (int ns = 0; ns < 4; ++ns) {
            const int o = (wc * 64 + ns * 16 + lm) * 32 + fpos8;
            Bf_h[ns] = *(const bf16x8*)&Bh_s[o];
            Bf_l[ns] = *(const bf16x8*)&Bl_s[o];
        }
#pragma unroll
        for (int ms = 0; ms < 4; ++ms) {
            const int o = (wr * 64 + ms * 16 + lm) * 32 + fpos8;
            const bf16x8 Af_h = *(const bf16x8*)&Ah_s[o];
            const bf16x8 Af_l = *(const bf16x8*)&Al_s[o];
#pragma unroll
            for (int ns = 0; ns < 4; ++ns) {
                acc[ms][ns] = __builtin_amdgcn_mfma_f32_16x16x32_bf16(Af_h, Bf_h[ns], acc[ms][ns], 0, 0, 0);
                acc[ms][ns] = __builtin_amdgcn_mfma_f32_16x16x32_bf16(Af_h, Bf_l[ns], acc[ms][ns], 0, 0, 0);
                acc[ms][ns] = __builtin_amdgcn_mfma_f32_16x16x32_bf16(Af_l, Bf_h[ns], acc[ms][ns], 0, 0, 0);
            }
        }
    }

    // ---- write C: D layout col=lane&15, row=quad*4+reg (verified R5-R11) ----
#pragma unroll
    for (int ms = 0; ms < 4; ++ms) {
        const int rowb = m0 + wr * 64 + ms * 16 + quad * 4;
#pragma unroll
        for (int ns = 0; ns < 4; ++ns) {
            const int col = n0 + wc * 64 + ns * 16 + lm;
#pragma unroll
            for (int r = 0; r < 4; ++r)
                fW[((size_t)(rowb + r) * I_SZ + i) * N_SZ + col] = acc[ms][ns][r];
        }
    }
}

// ---------------------------------------------------------------------------
// Kernel 2: routing via Gram matrices (unchanged).
// ---------------------------------------------------------------------------
__global__ __launch_bounds__(1024) void routing_kernel(
    const float* __restrict__ fW,  // [B, I, N]
    const float* __restrict__ p,   // [B, I]
    float* __restrict__ c_out,     // [B, J, E]
    float* __restrict__ r_out)     // [B, I, J]
{
    const int b   = blockIdx.x;
    const int tid = threadIdx.x;
    const int j   = tid >> 4;      // 0..63
    const int sub = tid & 15;      // e-chunk [sub*8, sub*8+8)

    __shared__ float G_sh[64][49];
    __shared__ float s_sh[64][9];
    __shared__ float w_sh[2][64][9];
    __shared__ float p_sh[8];

    if (tid < I_SZ) p_sh[tid] = p[(size_t)b * I_SZ + tid];

    float4 fw[I_SZ][2];
    const float* base = fW + (size_t)b * I_SZ * N_SZ + j * E_SZ + sub * 8;
#pragma unroll
    for (int i = 0; i < I_SZ; ++i) {
        fw[i][0] = *(const float4*)(base + (size_t)i * N_SZ);
        fw[i][1] = *(const float4*)(base + (size_t)i * N_SZ + 4);
    }

    // ---- Phase 1: Gram + row sums (reduce over 16 sub-lanes) ----
#pragma unroll
    for (int i = 0; i < I_SZ; ++i) {
        float s = fw[i][0].x + fw[i][0].y + fw[i][0].z + fw[i][0].w
                + fw[i][1].x + fw[i][1].y + fw[i][1].z + fw[i][1].w;
        s += __shfl_xor(s, 1); s += __shfl_xor(s, 2);
        s += __shfl_xor(s, 4); s += __shfl_xor(s, 8);
        if (sub == 0) s_sh[j][i] = s;
#pragma unroll
        for (int i2 = i; i2 < I_SZ; ++i2) {
            float g = fw[i][0].x * fw[i2][0].x + fw[i][0].y * fw[i2][0].y
                    + fw[i][0].z * fw[i2][0].z + fw[i][0].w * fw[i2][0].w
                    + fw[i][1].x * fw[i2][1].x + fw[i][1].y * fw[i2][1].y
                    + fw[i][1].z * fw[i2][1].z + fw[i][1].w * fw[i2][1].w;
            g += __shfl_xor(g, 1); g += __shfl_xor(g, 2);
            g += __shfl_xor(g, 4); g += __shfl_xor(g, 8);
            if (sub == 0) { G_sh[j][i * 7 + i2] = g; G_sh[j][i2 * 7 + i] = g; }
        }
    }
    __syncthreads();

    // ---- Phase 2: 10 iterations on the 7x7 system ----
    for (int t = 0; t < ITERS; ++t) {
        if (tid < I_SZ * 64) {                 // waves 0..6
            const int ii = tid >> 6;
            const int jj = tid & 63;
            float l;
            if (t == 0) {
                l = s_sh[jj][ii];              // c0 = ones
            } else {
                const int rb = t & 1;
                l = 0.f;
#pragma unroll
                for (int i2 = 0; i2 < I_SZ; ++i2)
                    l = fmaf(w_sh[rb][jj][i2], G_sh[jj][ii * 7 + i2], l);
            }
            float mx = l;
#pragma unroll
            for (int off = 32; off > 0; off >>= 1)
                mx = fmaxf(mx, __shfl_xor(mx, off));
            float ex = __expf(l - mx);
            float sm = ex;
#pragma unroll
            for (int off = 32; off > 0; off >>= 1)
                sm += __shfl_xor(sm, off);
            float r = ex / sm;
            if (t == ITERS - 1)
                r_out[(size_t)b * (I_SZ * J_SZ) + ii * 64 + jj] = r;
            w_sh[(t + 1) & 1][jj][ii] = p_sh[ii] * r;
        }
        __syncthreads();
    }

    // ---- Phase 3: c from registers ----
    float4 a0 = make_float4(0.f, 0.f, 0.f, 0.f);
    float4 a1 = make_float4(0.f, 0.f, 0.f, 0.f);
#pragma unroll
    for (int i = 0; i < I_SZ; ++i) {
        float wv = w_sh[ITERS & 1][j][i];
        a0.x = fmaf(wv, fw[i][0].x, a0.x); a0.y = fmaf(wv, fw[i][0].y, a0.y);
        a0.z = fmaf(wv, fw[i][0].z, a0.z); a0.w = fmaf(wv, fw[i][0].w, a0.w);
        a1.x = fmaf(wv, fw[i][1].x, a1.x); a1.y = fmaf(wv, fw[i][1].y, a1.y);
        a1.z = fmaf(wv, fw[i][1].z, a1.z); a1.w = fmaf(wv, fw[i][1].w, a1.w);
    }
    float* dst = c_out + (size_t)b * N_SZ + j * E_SZ + sub * 8;
    *(float4*)(dst)     = a0;
    *(float4*)(dst + 4) = a1;
}

extern "C" void kernel_launch(void* const* d_in, const int* in_sizes, int n_in,
                              void* d_out, int out_size, void* d_ws, size_t ws_size,
                              hipStream_t stream) {
    const float* f = (const float*)d_in[0];   // [512,7,512]
    const float* p = (const float*)d_in[1];   // [512,7]
    const float* W = (const float*)d_in[2];   // [7,512,64,128]
    float* out = (float*)d_out;               // c (512*64*128) then r (512*7*64)
    float* fW  = (float*)d_ws;                // 117.4 MB scratch

    vote_gemm_mfma<<<dim3(N_SZ / 128, B_SZ / 128, I_SZ), 256, 0, stream>>>(f, W, fW);
    routing_kernel<<<B_SZ, 1024, 0, stream>>>(fW, p, out, out + (size_t)B_SZ * N_SZ);
}

// Round 8
// 295.203 us; speedup vs baseline: 1.8798x; 1.1540x over previous
//
#include <hip/hip_runtime.h>
#include <hip/hip_bf16.h>

#define B_SZ 512
#define I_SZ 7
#define D_SZ 512
#define J_SZ 64
#define E_SZ 128
#define N_SZ 8192
#define ITERS 10

typedef __attribute__((ext_vector_type(8))) short bf16x8;
typedef __attribute__((ext_vector_type(4))) float f32x4;

#define AST 40   // LDS row stride in bf16 shorts (32 k + 8 pad), 16B-aligned rows
#define BST 40

#if defined(__has_builtin)
#if __has_builtin(__builtin_amdgcn_cvt_pk_bf16_f32)
#define HAVE_CVT_PK_BF16 1
#endif
#endif

// Split a PAIR of fp32 into packed-bf16 hi and lo words (RNE both stages).
__device__ inline void split2(float x0, float x1, unsigned& hp, unsigned& lp) {
#ifdef HAVE_CVT_PK_BF16
    auto h = __builtin_amdgcn_cvt_pk_bf16_f32(x0, x1);
    hp = __builtin_bit_cast(unsigned, h);
    union { unsigned u; float f; } b0, b1;
    b0.u = hp << 16;
    b1.u = hp & 0xFFFF0000u;
    auto l = __builtin_amdgcn_cvt_pk_bf16_f32(x0 - b0.f, x1 - b1.f);
    lp = __builtin_bit_cast(unsigned, l);
#else
    union { float f; unsigned u; } u0, u1;
    u0.f = x0; u1.f = x1;
    unsigned r0 = u0.u + 0x7FFF + ((u0.u >> 16) & 1);
    unsigned r1 = u1.u + 0x7FFF + ((u1.u >> 16) & 1);
    hp = __builtin_amdgcn_perm(r1, r0, 0x07060302);   // [r1.hi16 | r0.hi16]
    union { unsigned u; float f; } h0, h1;
    h0.u = r0 & 0xFFFF0000u;
    h1.u = r1 & 0xFFFF0000u;
    union { float f; unsigned u; } s0, s1;
    s0.f = x0 - h0.f; s1.f = x1 - h1.f;
    unsigned q0 = s0.u + 0x7FFF + ((s0.u >> 16) & 1);
    unsigned q1 = s1.u + 0x7FFF + ((s1.u >> 16) & 1);
    lp = __builtin_amdgcn_perm(q1, q0, 0x07060302);
#endif
}

// ---------------------------------------------------------------------------
// Kernel 1 (R13 == R5 verbatim): the measured-best GEMM config (134.7 us).
// Six structural variants (R6-R12: 256^2 tiles, gload_lds, phase schedules,
// conflict-free swizzle, occupancy hints) all measured slower. R12 proved the
// +8-pad's bank conflicts are NOT on the critical path (latency-bound regime);
// the pad layout's lower VGPR (80) and higher residency win. Do not touch.
// ---------------------------------------------------------------------------
__global__ __launch_bounds__(256) void vote_gemm_mfma(
    const float* __restrict__ f,   // [B, I, D]
    const float* __restrict__ W,   // [I, D, N]
    float* __restrict__ fW)        // [B, I, N]
{
    const int i  = blockIdx.z;
    const int m0 = blockIdx.y * 128;
    const int n0 = blockIdx.x * 128;
    const int th = threadIdx.x;

    __shared__ short As_hi[128 * AST], As_lo[128 * AST];  // [m][k]
    __shared__ short Bs_hi[128 * BST], Bs_lo[128 * BST];  // [n][k] (transposed)

    // A staging map: thread -> (row m, k-half of 16)
    const int am  = th >> 1;          // 0..127
    const int akg = th & 1;           // k offset 16*akg
    // B staging map: thread -> (col n, k-half); lanes span n (coalesced rows)
    const int bn  = th & 127;         // 0..127
    const int bkh = th >> 7;          // 0/1

    const float* fA = f + (size_t)(m0 + am) * (I_SZ * D_SZ) + (size_t)i * D_SZ + akg * 16;
    const float* WB = W + (size_t)i * D_SZ * N_SZ + n0 + bn;

    const int wave = th >> 6, lane = th & 63;
    const int wr = wave >> 1, wc = wave & 1;   // wave -> 64x64 quadrant
    const int lm = lane & 15, quad = lane >> 4;

    f32x4 acc[4][4];
#pragma unroll
    for (int a = 0; a < 4; ++a)
#pragma unroll
        for (int c = 0; c < 4; ++c)
            acc[a][c] = (f32x4){0.f, 0.f, 0.f, 0.f};

    // ---- prefetch first k-tile ----
    float av[16], bv[16];
    {
        float4 t0 = *(const float4*)(fA);
        float4 t1 = *(const float4*)(fA + 4);
        float4 t2 = *(const float4*)(fA + 8);
        float4 t3 = *(const float4*)(fA + 12);
        av[0]=t0.x; av[1]=t0.y; av[2]=t0.z; av[3]=t0.w;
        av[4]=t1.x; av[5]=t1.y; av[6]=t1.z; av[7]=t1.w;
        av[8]=t2.x; av[9]=t2.y; av[10]=t2.z; av[11]=t2.w;
        av[12]=t3.x; av[13]=t3.y; av[14]=t3.z; av[15]=t3.w;
        const float* pb = WB + (size_t)(bkh * 16) * N_SZ;
#pragma unroll
        for (int r = 0; r < 16; ++r) bv[r] = pb[(size_t)r * N_SZ];
    }

    for (int k0 = 0; k0 < D_SZ; k0 += 32) {
        // ---- pair-split into packed hi/lo words ----
        uint4 ah0, al0, ah1, al1, bh0, bl0, bh1, bl1;
        split2(av[0],  av[1],  ah0.x, al0.x);
        split2(av[2],  av[3],  ah0.y, al0.y);
        split2(av[4],  av[5],  ah0.z, al0.z);
        split2(av[6],  av[7],  ah0.w, al0.w);
        split2(av[8],  av[9],  ah1.x, al1.x);
        split2(av[10], av[11], ah1.y, al1.y);
        split2(av[12], av[13], ah1.z, al1.z);
        split2(av[14], av[15], ah1.w, al1.w);
        split2(bv[0],  bv[1],  bh0.x, bl0.x);
        split2(bv[2],  bv[3],  bh0.y, bl0.y);
        split2(bv[4],  bv[5],  bh0.z, bl0.z);
        split2(bv[6],  bv[7],  bh0.w, bl0.w);
        split2(bv[8],  bv[9],  bh1.x, bl1.x);
        split2(bv[10], bv[11], bh1.y, bl1.y);
        split2(bv[12], bv[13], bh1.z, bl1.z);
        split2(bv[14], bv[15], bh1.w, bl1.w);

        __syncthreads();   // previous tile's frag reads complete
        *(uint4*)&As_hi[am * AST + akg * 16]     = ah0;
        *(uint4*)&As_hi[am * AST + akg * 16 + 8] = ah1;
        *(uint4*)&As_lo[am * AST + akg * 16]     = al0;
        *(uint4*)&As_lo[am * AST + akg * 16 + 8] = al1;
        *(uint4*)&Bs_hi[bn * BST + bkh * 16]     = bh0;
        *(uint4*)&Bs_hi[bn * BST + bkh * 16 + 8] = bh1;
        *(uint4*)&Bs_lo[bn * BST + bkh * 16]     = bl0;
        *(uint4*)&Bs_lo[bn * BST + bkh * 16 + 8] = bl1;
        __syncthreads();   // staging visible

        // ---- prefetch next k-tile (latency hides under the MFMA phase) ----
        if (k0 + 32 < D_SZ) {
            const float* pa = fA + k0 + 32;
            float4 t0 = *(const float4*)(pa);
            float4 t1 = *(const float4*)(pa + 4);
            float4 t2 = *(const float4*)(pa + 8);
            float4 t3 = *(const float4*)(pa + 12);
            av[0]=t0.x; av[1]=t0.y; av[2]=t0.z; av[3]=t0.w;
            av[4]=t1.x; av[5]=t1.y; av[6]=t1.z; av[7]=t1.w;
            av[8]=t2.x; av[9]=t2.y; av[10]=t2.z; av[11]=t2.w;
            av[12]=t3.x; av[13]=t3.y; av[14]=t3.z; av[15]=t3.w;
            const float* pb = WB + (size_t)(k0 + 32 + bkh * 16) * N_SZ;
#pragma unroll
            for (int r = 0; r < 16; ++r) bv[r] = pb[(size_t)r * N_SZ];
        }

        // ---- fragment loads + MFMA ----
        bf16x8 Ah[4], Al[4], Bh[4], Bl[4];
#pragma unroll
        for (int t = 0; t < 4; ++t) {
            const int ar = (wr * 64 + t * 16 + lm) * AST + quad * 8;
            Ah[t] = *(const bf16x8*)&As_hi[ar];
            Al[t] = *(const bf16x8*)&As_lo[ar];
            const int br = (wc * 64 + t * 16 + lm) * BST + quad * 8;
            Bh[t] = *(const bf16x8*)&Bs_hi[br];
            Bl[t] = *(const bf16x8*)&Bs_lo[br];
        }
#pragma unroll
        for (int tm = 0; tm < 4; ++tm)
#pragma unroll
            for (int tn = 0; tn < 4; ++tn) {
                acc[tm][tn] = __builtin_amdgcn_mfma_f32_16x16x32_bf16(Ah[tm], Bh[tn], acc[tm][tn], 0, 0, 0);
                acc[tm][tn] = __builtin_amdgcn_mfma_f32_16x16x32_bf16(Ah[tm], Bl[tn], acc[tm][tn], 0, 0, 0);
                acc[tm][tn] = __builtin_amdgcn_mfma_f32_16x16x32_bf16(Al[tm], Bh[tn], acc[tm][tn], 0, 0, 0);
            }
    }

    // ---- write C: D layout col=lane&15, row=quad*4+reg ----
#pragma unroll
    for (int tm = 0; tm < 4; ++tm) {
        const int rowb = m0 + wr * 64 + tm * 16 + quad * 4;
#pragma unroll
        for (int tn = 0; tn < 4; ++tn) {
            const int col = n0 + wc * 64 + tn * 16 + lm;
#pragma unroll
            for (int r = 0; r < 4; ++r)
                fW[((size_t)(rowb + r) * I_SZ + i) * N_SZ + col] = acc[tm][tn][r];
        }
    }
}

// ---------------------------------------------------------------------------
// Kernel 2 (R13): routing, register-light streaming rewrite.
// Old version held fw[7][2] float4 = 56 VGPRs live across all 3 phases in a
// 1024-thread block (hard 128-VGPR cap) -> spill risk + 1 block/CU max, and
// total-minus-GEMM has been pinned at ~160us in all 8 rounds (~6x the 20us
// memory floor). This version never holds more than one fW row pair:
//   Phase 1: stream pairs (vi held, vi2 re-loaded; re-reads are L2/L3-warm —
//            each block touches only its own 229 KB slice).
//   Phase 2: unchanged (7x7 iteration, same shfl trees).
//   Phase 3: re-stream fW (identical values -> c bit-identical; L2/L3-warm).
// Live set ~30 VGPR -> no spill, 2 blocks/CU co-resident, full MLP.
// All float math identical op-for-op to the previous version.
// ---------------------------------------------------------------------------
__global__ __launch_bounds__(1024) void routing_kernel(
    const float* __restrict__ fW,  // [B, I, N]
    const float* __restrict__ p,   // [B, I]
    float* __restrict__ c_out,     // [B, J, E]
    float* __restrict__ r_out)     // [B, I, J]
{
    const int b   = blockIdx.x;
    const int tid = threadIdx.x;
    const int j   = tid >> 4;      // 0..63
    const int sub = tid & 15;      // e-chunk [sub*8, sub*8+8)

    __shared__ float G_sh[64][49];
    __shared__ float s_sh[64][9];
    __shared__ float w_sh[2][64][9];
    __shared__ float p_sh[8];

    if (tid < I_SZ) p_sh[tid] = p[(size_t)b * I_SZ + tid];

    const float* base = fW + (size_t)b * I_SZ * N_SZ + j * E_SZ + sub * 8;

    // ---- Phase 1: Gram + row sums, streaming (vi held, vi2 re-loaded) ----
#pragma unroll
    for (int i = 0; i < I_SZ; ++i) {
        const float4 vi0 = *(const float4*)(base + (size_t)i * N_SZ);
        const float4 vi1 = *(const float4*)(base + (size_t)i * N_SZ + 4);
        float s = vi0.x + vi0.y + vi0.z + vi0.w
                + vi1.x + vi1.y + vi1.z + vi1.w;
        s += __shfl_xor(s, 1); s += __shfl_xor(s, 2);
        s += __shfl_xor(s, 4); s += __shfl_xor(s, 8);
        if (sub == 0) s_sh[j][i] = s;
#pragma unroll
        for (int i2 = i; i2 < I_SZ; ++i2) {
            float4 w0, w1;
            if (i2 == i) { w0 = vi0; w1 = vi1; }
            else {
                w0 = *(const float4*)(base + (size_t)i2 * N_SZ);
                w1 = *(const float4*)(base + (size_t)i2 * N_SZ + 4);
            }
            float g = vi0.x * w0.x + vi0.y * w0.y
                    + vi0.z * w0.z + vi0.w * w0.w
                    + vi1.x * w1.x + vi1.y * w1.y
                    + vi1.z * w1.z + vi1.w * w1.w;
            g += __shfl_xor(g, 1); g += __shfl_xor(g, 2);
            g += __shfl_xor(g, 4); g += __shfl_xor(g, 8);
            if (sub == 0) { G_sh[j][i * 7 + i2] = g; G_sh[j][i2 * 7 + i] = g; }
        }
    }
    __syncthreads();

    // ---- Phase 2: 10 iterations on the 7x7 system (unchanged) ----
    for (int t = 0; t < ITERS; ++t) {
        if (tid < I_SZ * 64) {                 // waves 0..6
            const int ii = tid >> 6;
            const int jj = tid & 63;
            float l;
            if (t == 0) {
                l = s_sh[jj][ii];              // c0 = ones
            } else {
                const int rb = t & 1;
                l = 0.f;
#pragma unroll
                for (int i2 = 0; i2 < I_SZ; ++i2)
                    l = fmaf(w_sh[rb][jj][i2], G_sh[jj][ii * 7 + i2], l);
            }
            float mx = l;
#pragma unroll
            for (int off = 32; off > 0; off >>= 1)
                mx = fmaxf(mx, __shfl_xor(mx, off));
            float ex = __expf(l - mx);
            float sm = ex;
#pragma unroll
            for (int off = 32; off > 0; off >>= 1)
                sm += __shfl_xor(sm, off);
            float r = ex / sm;
            if (t == ITERS - 1)
                r_out[(size_t)b * (I_SZ * J_SZ) + ii * 64 + jj] = r;
            w_sh[(t + 1) & 1][jj][ii] = p_sh[ii] * r;
        }
        __syncthreads();
    }

    // ---- Phase 3: c, re-streaming fW (values identical -> c bit-identical) ----
    float4 a0 = make_float4(0.f, 0.f, 0.f, 0.f);
    float4 a1 = make_float4(0.f, 0.f, 0.f, 0.f);
#pragma unroll
    for (int i = 0; i < I_SZ; ++i) {
        const float4 v0 = *(const float4*)(base + (size_t)i * N_SZ);
        const float4 v1 = *(const float4*)(base + (size_t)i * N_SZ + 4);
        const float wv = w_sh[ITERS & 1][j][i];
        a0.x = fmaf(wv, v0.x, a0.x); a0.y = fmaf(wv, v0.y, a0.y);
        a0.z = fmaf(wv, v0.z, a0.z); a0.w = fmaf(wv, v0.w, a0.w);
        a1.x = fmaf(wv, v1.x, a1.x); a1.y = fmaf(wv, v1.y, a1.y);
        a1.z = fmaf(wv, v1.z, a1.z); a1.w = fmaf(wv, v1.w, a1.w);
    }
    float* dst = c_out + (size_t)b * N_SZ + j * E_SZ + sub * 8;
    *(float4*)(dst)     = a0;
    *(float4*)(dst + 4) = a1;
}

extern "C" void kernel_launch(void* const* d_in, const int* in_sizes, int n_in,
                              void* d_out, int out_size, void* d_ws, size_t ws_size,
                              hipStream_t stream) {
    const float* f = (const float*)d_in[0];   // [512,7,512]
    const float* p = (const float*)d_in[1];   // [512,7]
    const float* W = (const float*)d_in[2];   // [7,512,64,128]
    float* out = (float*)d_out;               // c (512*64*128) then r (512*7*64)
    float* fW  = (float*)d_ws;                // 117.4 MB scratch

    vote_gemm_mfma<<<dim3(N_SZ / 128, B_SZ / 128, I_SZ), 256, 0, stream>>>(f, W, fW);
    routing_kernel<<<B_SZ, 1024, 0, stream>>>(fW, p, out, out + (size_t)B_SZ * N_SZ);
}